// Round 9
// baseline (446.400 us; speedup 1.0000x reference)
//
#include <hip/hip_runtime.h>
#include <hip/hip_bf16.h>

// ---------- types ----------
typedef __attribute__((ext_vector_type(8)))  __bf16 bf16x8;
typedef __attribute__((ext_vector_type(4)))  float  f32x4;
typedef __attribute__((ext_vector_type(16))) float  f32x16;

static __device__ __forceinline__ unsigned short f2bf(float x) {
    unsigned int u = __float_as_uint(x);
    unsigned int r = (u + 0x7FFFu + ((u >> 16) & 1u)) >> 16;
    return (unsigned short)r;
}
static __device__ __forceinline__ float bf2f(unsigned short u) {
    return __uint_as_float(((unsigned int)u) << 16);
}

// 2^x via v_exp_f32; s_nop covers the trans-op result hazard inside inline asm.
static __device__ __forceinline__ float fast_exp2(float x) {
    float r;
    asm volatile("v_exp_f32 %0, %1\n\ts_nop 1" : "=v"(r) : "v"(x));
    return r;
}
// packed f32x2 -> bf16x2 (u32); lo <- a, hi <- b
static __device__ __forceinline__ unsigned int cvt_pk_bf16(float a, float b) {
    unsigned int r;
    asm("v_cvt_pk_bf16_f32 %0, %1, %2" : "=v"(r) : "v"(a), "v"(b));
    return r;
}

// async global->LDS, 16B per lane; lds base wave-uniform (lane*16 auto-offset)
static __device__ __forceinline__ void gload_lds16(const ushort* g, ushort* l) {
    __builtin_amdgcn_global_load_lds((const __attribute__((address_space(1))) void*)g,
                                     (__attribute__((address_space(3))) void*)l, 16, 0, 0);
}

// raw barrier + scheduling/memory fence (no vmcnt drain, unlike __syncthreads)
static __device__ __forceinline__ void barrier_fence() {
    __builtin_amdgcn_s_barrier();
    __builtin_amdgcn_sched_barrier(0);
    asm volatile("" ::: "memory");
}

// T1: XCD-aware chunked remap (requires nwg % 8 == 0; all grids here comply)
static __device__ __forceinline__ int xcd_swz(int id, int nwg) {
    return (id & 7) * (nwg >> 3) + (id >> 3);
}

// ---------- elementwise cast f32 -> bf16 ----------
__global__ __launch_bounds__(256) void cast_bf16_kernel(const float* __restrict__ in,
                                                        ushort* __restrict__ out, int n4) {
    int i = blockIdx.x * 256 + threadIdx.x;
    if (i < n4) {
        float4 v = reinterpret_cast<const float4*>(in)[i];
        ushort4 o;
        o.x = f2bf(v.x); o.y = f2bf(v.y); o.z = f2bf(v.z); o.w = f2bf(v.w);
        reinterpret_cast<ushort4*>(out)[i] = o;
    }
}

// ---------- transpose + cast: in[K][N] f32 -> out[N][K] bf16 ----------
__global__ __launch_bounds__(256) void transpose_cast_kernel(const float* __restrict__ in,
                                                             ushort* __restrict__ out,
                                                             int K, int N) {
    __shared__ float tile[32][33];
    const int tx = threadIdx.x;
    const int ty = threadIdx.y;
    const int n0 = blockIdx.x * 32;
    const int k0 = blockIdx.y * 32;
    for (int i = ty; i < 32; i += 8)
        tile[i][tx] = in[(size_t)(k0 + i) * N + n0 + tx];
    __syncthreads();
    for (int i = ty; i < 32; i += 8)
        out[(size_t)(n0 + i) * K + k0 + tx] = f2bf(tile[tx][i]);
}

// three 1024x1024 transposes (Wq,Wk,Wv) in one launch; z picks the source
__global__ __launch_bounds__(256) void transpose_cast3_kernel(const float* __restrict__ w0,
                                                              const float* __restrict__ w1,
                                                              const float* __restrict__ w2,
                                                              ushort* __restrict__ out) {
    __shared__ float tile[32][33];
    const int tx = threadIdx.x;
    const int ty = threadIdx.y;
    const int n0 = blockIdx.x * 32;
    const int k0 = blockIdx.y * 32;
    const int z  = blockIdx.z;
    const float* in = (z == 0) ? w0 : (z == 1 ? w1 : w2);
    ushort* o = out + (size_t)z * 1024 * 1024;
    for (int i = ty; i < 32; i += 8)
        tile[i][tx] = in[(size_t)(k0 + i) * 1024 + n0 + tx];
    __syncthreads();
    for (int i = ty; i < 32; i += 8)
        o[(size_t)(n0 + i) * 1024 + k0 + tx] = f2bf(tile[tx][i]);
}

// ============================================================================
// Deep-pipelined GEMM (T2+T3+T4+T5): C[M][N] = A[M][K] * Bt[N][K]^T + bias.
// BM=256, BN=128, BK=64. 512 threads = 8 waves (4M x 2N), 64x64 out per wave.
// LDS: 3 K-tile buffers (144 KB, 1 block/CU). Prefetch 2 tiles ahead with
// counted s_waitcnt vmcnt(6) (6 gloads/wave/tile), one raw barrier per tile.
// LDS rows are 128B: linear layout would 16-way bank-conflict every
// ds_read_b128 fragment column. Swizzle: 16B-chunk index ^= (row&7), applied
// BOTH sides (rule 21): pre-swizzled global source addr + linear gload dst,
// and the same XOR on ds_read addresses. bank = chunk*4 mod 32 -> 8 rows
// spread over all 8 chunk slots -> 2-way (free).
// ============================================================================
template<int RELU, int OUTBF, int QKV>
__global__ __launch_bounds__(512, 2) void gemm_8p(const ushort* __restrict__ A,
                                                  const ushort* __restrict__ Bt,
                                                  const float* __restrict__ b0,
                                                  const float* __restrict__ b1_,
                                                  const float* __restrict__ b2_,
                                                  void* __restrict__ Cp,
                                                  int M, int N, int K) {
    __shared__ ushort As[3][16384];   // [256][64] swizzled, 32 KB per buffer
    __shared__ ushort Bs[3][8192];    // [128][64] swizzled, 16 KB per buffer
    const int tid  = threadIdx.x;
    const int lane = tid & 63;
    const int w    = tid >> 6;        // 0..7
    const int wr   = w >> 1;          // 0..3
    const int wc   = w & 1;           // 0..1
    const int nwg  = gridDim.x * gridDim.y;
    int wid = xcd_swz(blockIdx.y * gridDim.x + blockIdx.x, nwg);
    const int bx = wid % gridDim.x;
    const int by = wid / gridDim.x;
    const int m0 = by * 256;
    const int n0 = bx * 128;
    const int lr = lane & 15;
    const int lg = lane >> 4;         // 0..3 (k-octet within 32)

    // hoisted fragment LDS element offsets (swizzled)
    int offA[4][2], offB[4][2];
#pragma unroll
    for (int i = 0; i < 4; i++) {
        const int row = wr * 64 + i * 16 + lr;
#pragma unroll
        for (int ks = 0; ks < 2; ks++)
            offA[i][ks] = row * 64 + (((ks * 4 + lg) ^ (row & 7)) << 3);
    }
#pragma unroll
    for (int j = 0; j < 4; j++) {
        const int row = wc * 64 + j * 16 + lr;
#pragma unroll
        for (int ks = 0; ks < 2; ks++)
            offB[j][ks] = row * 64 + (((ks * 4 + lg) ^ (row & 7)) << 3);
    }

    // staging: A = 4 rounds, B = 2 rounds of (8 waves x 64 lanes x 16B).
    // round slot = rnd*512 + w*64 + lane -> row = slot>>3, chunk-pos = lane&7.
    // global source chunk pre-swizzled: cp ^ (row&7).
    const int cp = lane & 7;
    const ushort* gA[4];
    int ldsA[4];
#pragma unroll
    for (int a = 0; a < 4; a++) {
        const int row = a * 64 + w * 8 + (lane >> 3);
        gA[a]  = A + (size_t)(m0 + row) * K + ((cp ^ (row & 7)) << 3);
        ldsA[a] = (a * 512 + w * 64) * 8;
    }
    const ushort* gB[2];
    int ldsB[2];
#pragma unroll
    for (int b = 0; b < 2; b++) {
        const int row = b * 64 + w * 8 + (lane >> 3);
        gB[b]  = Bt + (size_t)(n0 + row) * K + ((cp ^ (row & 7)) << 3);
        ldsB[b] = (b * 512 + w * 64) * 8;
    }

    f32x4 acc[4][4];
    const f32x4 z = {0.f, 0.f, 0.f, 0.f};
#pragma unroll
    for (int i = 0; i < 4; i++)
#pragma unroll
        for (int j = 0; j < 4; j++) acc[i][j] = z;

    const int nt = K >> 6;            // K/64 (>= 16 for all shapes here)

    // prologue: issue tiles 0 and 1 (12 loads/wave in flight)
#pragma unroll
    for (int t = 0; t < 2; ++t) {
        const int kn = t * 64;
#pragma unroll
        for (int a = 0; a < 4; a++) gload_lds16(gA[a] + kn, &As[t][ldsA[a]]);
#pragma unroll
        for (int b = 0; b < 2; b++) gload_lds16(gB[b] + kn, &Bs[t][ldsB[b]]);
    }

    int cur = 0;                      // t % 3
    for (int t = 0; t < nt; ++t) {
        if (t + 1 < nt) asm volatile("s_waitcnt vmcnt(6)" ::: "memory");  // tile t landed
        else            asm volatile("s_waitcnt vmcnt(0)" ::: "memory");
        barrier_fence();              // tile t visible everywhere; buf (t+2)%3 free

        if (t + 2 < nt) {
            const int bi = (cur + 2 > 2) ? cur - 1 : cur + 2;   // (t+2)%3
            const int kn = (t + 2) * 64;
#pragma unroll
            for (int a = 0; a < 4; a++) gload_lds16(gA[a] + kn, &As[bi][ldsA[a]]);
#pragma unroll
            for (int b = 0; b < 2; b++) gload_lds16(gB[b] + kn, &Bs[bi][ldsB[b]]);
        }

        const ushort* Asb = As[cur];
        const ushort* Bsb = Bs[cur];

        // ks = 0 half
        {
            bf16x8 af[4], bfr[4];
#pragma unroll
            for (int i = 0; i < 4; i++)
                af[i] = *reinterpret_cast<const bf16x8*>(&Asb[offA[i][0]]);
#pragma unroll
            for (int j = 0; j < 4; j++)
                bfr[j] = *reinterpret_cast<const bf16x8*>(&Bsb[offB[j][0]]);
            __builtin_amdgcn_s_setprio(1);
#pragma unroll
            for (int i = 0; i < 4; i++)
#pragma unroll
                for (int j = 0; j < 4; j++)
                    acc[i][j] = __builtin_amdgcn_mfma_f32_16x16x32_bf16(af[i], bfr[j], acc[i][j], 0, 0, 0);
            __builtin_amdgcn_s_setprio(0);
        }
        // ks = 1 half
        {
            bf16x8 af[4], bfr[4];
#pragma unroll
            for (int i = 0; i < 4; i++)
                af[i] = *reinterpret_cast<const bf16x8*>(&Asb[offA[i][1]]);
#pragma unroll
            for (int j = 0; j < 4; j++)
                bfr[j] = *reinterpret_cast<const bf16x8*>(&Bsb[offB[j][1]]);
            __builtin_amdgcn_s_setprio(1);
#pragma unroll
            for (int i = 0; i < 4; i++)
#pragma unroll
                for (int j = 0; j < 4; j++)
                    acc[i][j] = __builtin_amdgcn_mfma_f32_16x16x32_bf16(af[i], bfr[j], acc[i][j], 0, 0, 0);
            __builtin_amdgcn_s_setprio(0);
        }

        cur = (cur == 2) ? 0 : cur + 1;
    }

    // epilogue
    const float* bias;
    float qscale = 1.0f;
    if (QKV) {
        bias = (n0 < 1024) ? b0 : (n0 < 2048 ? b1_ : b2_);
        if (n0 < 1024) qscale = 0.18033688f;   // 0.125*log2(e) folded into Q
    } else {
        bias = b0;
    }
    const int nb = QKV ? (n0 & 1023) : n0;
    const int rbase = (lane >> 4) * 4;
#pragma unroll
    for (int i = 0; i < 4; i++) {
#pragma unroll
        for (int j = 0; j < 4; j++) {
            const int cloc = wc * 64 + j * 16 + lr;
            const float bv = bias[nb + cloc];
#pragma unroll
            for (int r = 0; r < 4; r++) {
                const int row = m0 + wr * 64 + i * 16 + rbase + r;
                float v = acc[i][j][r] + bv;
                if (RELU) v = v > 0.f ? v : 0.f;
                if (QKV)  v *= qscale;
                if (OUTBF) ((ushort*)Cp)[(size_t)row * N + n0 + cloc] = f2bf(v);
                else       ((float*)Cp)[(size_t)row * N + n0 + cloc] = v;
            }
        }
    }
}

// ---------- flash attention, 32x32 swapped-QK^T, in-register P (T12) ----------
#define ASWZ(row, col) ((row) * 64 + ((col) ^ ((((row) ^ ((row) >> 3)) & 7) << 3)))

__global__ __launch_bounds__(256, 3) void attn_kernel(const ushort* __restrict__ QKV,
                                                      ushort* __restrict__ O) {
    __shared__ ushort Ks[2][4096];
    __shared__ ushort Vt[2][4096];
    const int tid  = threadIdx.x;
    const int lane = tid & 63;
    const int w    = tid >> 6;
    const int l31  = lane & 31;
    const int hi   = lane >> 5;

    int blk = xcd_swz(blockIdx.x, gridDim.x);
    const int qb = blk & 15;
    const int h  = (blk >> 4) & 15;
    const int b  = blk >> 8;
    const int s0 = qb * 128 + w * 32;
    const size_t rowb   = (size_t)b * 2048;
    const size_t base_q = rowb * 3072 + (size_t)h * 64;
    const size_t base_k = base_q + 1024;
    const size_t base_v = base_q + 2048;
    const size_t base_o = rowb * 1024 + (size_t)h * 64;

    bf16x8 qf[4];
#pragma unroll
    for (int ks = 0; ks < 4; ks++)
        qf[ks] = *reinterpret_cast<const bf16x8*>(
            &QKV[base_q + (size_t)(s0 + l31) * 3072 + ks * 16 + 8 * hi]);

    int off8[2][4];
#pragma unroll
    for (int sub = 0; sub < 2; sub++)
#pragma unroll
        for (int ks = 0; ks < 4; ks++)
            off8[sub][ks] = ASWZ(sub * 32 + l31, ks * 16 + 8 * hi);

    const int tS  = tid >> 3;
    const int ccS = tid & 7;
    int vwoff[2][8];
#pragma unroll
    for (int i = 0; i < 2; i++)
#pragma unroll
        for (int jj = 0; jj < 8; jj++)
            vwoff[i][jj] = ASWZ(ccS * 8 + jj, tS + i * 32);
    const int t1  = tS + 32;
    const int sz0 = (tS ^ (tS >> 3)) & 7;
    const int sz1 = (t1 ^ (t1 >> 3)) & 7;
    const ushort* pK0 = QKV + base_k + (size_t)tS * 3072 + (ccS ^ sz0) * 8;
    const ushort* pK1 = QKV + base_k + (size_t)t1 * 3072 + (ccS ^ sz1) * 8;
    const ushort* pV0 = QKV + base_v + (size_t)tS * 3072 + ccS * 8;
    const ushort* pV1 = QKV + base_v + (size_t)t1 * 3072 + ccS * 8;
    const size_t step = (size_t)64 * 3072;

    gload_lds16(pK0, &Ks[0][w * 512]);
    gload_lds16(pK1, &Ks[0][2048 + w * 512]);
    {
        int4 v0 = *reinterpret_cast<const int4*>(pV0);
        int4 v1 = *reinterpret_cast<const int4*>(pV1);
        const ushort* vs0 = reinterpret_cast<const ushort*>(&v0);
        const ushort* vs1 = reinterpret_cast<const ushort*>(&v1);
#pragma unroll
        for (int jj = 0; jj < 8; jj++) Vt[0][vwoff[0][jj]] = vs0[jj];
#pragma unroll
        for (int jj = 0; jj < 8; jj++) Vt[0][vwoff[1][jj]] = vs1[jj];
    }
    pK0 += step; pK1 += step; pV0 += step; pV1 += step;
    __syncthreads();

    f32x16 oacc0, oacc1;
    for (int i = 0; i < 16; i++) { oacc0[i] = 0.f; oacc1[i] = 0.f; }
    float lacc = 0.f;
    int cur = 0;

    for (int it = 0; it < 32; ++it) {
        int4 nv0, nv1;
        if (it < 31) {
            gload_lds16(pK0, &Ks[cur ^ 1][w * 512]);
            gload_lds16(pK1, &Ks[cur ^ 1][2048 + w * 512]);
            nv0 = *reinterpret_cast<const int4*>(pV0);
            nv1 = *reinterpret_cast<const int4*>(pV1);
            pK0 += step; pK1 += step; pV0 += step; pV1 += step;
        }

        f32x16 sa0, sa1;
        for (int i = 0; i < 16; i++) { sa0[i] = 0.f; sa1[i] = 0.f; }
        __builtin_amdgcn_s_setprio(1);
#pragma unroll
        for (int ks = 0; ks < 4; ks++) {
            bf16x8 k0 = *reinterpret_cast<const bf16x8*>(&Ks[cur][off8[0][ks]]);
            sa0 = __builtin_amdgcn_mfma_f32_32x32x16_bf16(k0, qf[ks], sa0, 0, 0, 0);
        }
#pragma unroll
        for (int ks = 0; ks < 4; ks++) {
            bf16x8 k1 = *reinterpret_cast<const bf16x8*>(&Ks[cur][off8[1][ks]]);
            sa1 = __builtin_amdgcn_mfma_f32_32x32x16_bf16(k1, qf[ks], sa1, 0, 0, 0);
        }
        __builtin_amdgcn_s_setprio(0);

        unsigned pk0[8], pk1[8];
#pragma unroll
        for (int i = 0; i < 8; i++) {
            float plo = fast_exp2(sa0[2 * i]);
            float phi = fast_exp2(sa0[2 * i + 1]);
            lacc += plo + phi;
            pk0[i] = cvt_pk_bf16(plo, phi);
        }
#pragma unroll
        for (int i = 0; i < 8; i++) {
            float plo = fast_exp2(sa1[2 * i]);
            float phi = fast_exp2(sa1[2 * i + 1]);
            lacc += plo + phi;
            pk1[i] = cvt_pk_bf16(plo, phi);
        }

        __builtin_amdgcn_s_setprio(1);
#pragma unroll
        for (int ks = 0; ks < 4; ks++) {
            const int bi = 4 * (ks & 1);
            unsigned a, bb, c, d;
            if (ks < 2) { a = pk0[bi]; bb = pk0[bi + 1]; c = pk0[bi + 2]; d = pk0[bi + 3]; }
            else        { a = pk1[bi]; bb = pk1[bi + 1]; c = pk1[bi + 2]; d = pk1[bi + 3]; }
            asm("v_permlane32_swap_b32 %0, %1" : "+v"(a), "+v"(c));
            asm("v_permlane32_swap_b32 %0, %1" : "+v"(bb), "+v"(d));
            union { unsigned u[4]; bf16x8 v; } fr;
            fr.u[0] = a; fr.u[1] = bb; fr.u[2] = c; fr.u[3] = d;
            bf16x8 v0 = *reinterpret_cast<const bf16x8*>(&Vt[cur][off8[0][ks]]);
            oacc0 = __builtin_amdgcn_mfma_f32_32x32x16_bf16(fr.v, v0, oacc0, 0, 0, 0);
            bf16x8 v1 = *reinterpret_cast<const bf16x8*>(&Vt[cur][off8[1][ks]]);
            oacc1 = __builtin_amdgcn_mfma_f32_32x32x16_bf16(fr.v, v1, oacc1, 0, 0, 0);
        }
        __builtin_amdgcn_s_setprio(0);

        if (it < 31) {
            const ushort* vs0 = reinterpret_cast<const ushort*>(&nv0);
            const ushort* vs1 = reinterpret_cast<const ushort*>(&nv1);
#pragma unroll
            for (int jj = 0; jj < 8; jj++) Vt[cur ^ 1][vwoff[0][jj]] = vs0[jj];
#pragma unroll
            for (int jj = 0; jj < 8; jj++) Vt[cur ^ 1][vwoff[1][jj]] = vs1[jj];
        }
        __syncthreads();
        cur ^= 1;
    }

    const float ltot = lacc + __shfl_xor(lacc, 32);
    const float inv  = 1.f / ltot;
#pragma unroll
    for (int r = 0; r < 16; r++) {
        const int qloc = (r & 3) + 8 * (r >> 2) + 4 * hi;
        const float invq = __shfl(inv, qloc);
        const size_t rowoff = base_o + (size_t)(s0 + qloc) * 1024 + l31;
        O[rowoff]      = f2bf(oacc0[r] * invq);
        O[rowoff + 32] = f2bf(oacc1[r] * invq);
    }
}

// ---------- residual + layernorm variants ----------
__global__ __launch_bounds__(256) void ln_res_fb(const float* __restrict__ x,
                                                 const ushort* __restrict__ y,
                                                 const float* __restrict__ g,
                                                 const float* __restrict__ be,
                                                 ushort* __restrict__ outb) {
    const int row = blockIdx.x;
    const int tid = threadIdx.x;
    const float4 xv = reinterpret_cast<const float4*>(x + (size_t)row * 1024)[tid];
    const ushort4 yv = reinterpret_cast<const ushort4*>(y + (size_t)row * 1024)[tid];
    float v[4] = {xv.x + bf2f(yv.x), xv.y + bf2f(yv.y), xv.z + bf2f(yv.z), xv.w + bf2f(yv.w)};
    float s  = v[0] + v[1] + v[2] + v[3];
    float s2 = v[0]*v[0] + v[1]*v[1] + v[2]*v[2] + v[3]*v[3];
    for (int off = 32; off; off >>= 1) { s += __shfl_down(s, off); s2 += __shfl_down(s2, off); }
    __shared__ float red[8];
    const int w = tid >> 6, lane = tid & 63;
    if (lane == 0) { red[w] = s; red[4 + w] = s2; }
    __syncthreads();
    if (tid == 0) {
        const float ts  = red[0] + red[1] + red[2] + red[3];
        const float ts2 = red[4] + red[5] + red[6] + red[7];
        const float mu  = ts * (1.f / 1024.f);
        const float var = ts2 * (1.f / 1024.f) - mu * mu;
        red[0] = mu;
        red[1] = rsqrtf(var + 1e-5f);
    }
    __syncthreads();
    const float mu = red[0], rs = red[1];
    const float4 gv = reinterpret_cast<const float4*>(g)[tid];
    const float4 bv = reinterpret_cast<const float4*>(be)[tid];
    ushort4 ob;
    ob.x = f2bf((v[0] - mu) * rs * gv.x + bv.x);
    ob.y = f2bf((v[1] - mu) * rs * gv.y + bv.y);
    ob.z = f2bf((v[2] - mu) * rs * gv.z + bv.z);
    ob.w = f2bf((v[3] - mu) * rs * gv.w + bv.w);
    reinterpret_cast<ushort4*>(outb + (size_t)row * 1024)[tid] = ob;
}

__global__ __launch_bounds__(256) void ln_res_bb(const ushort* __restrict__ x,
                                                 const ushort* __restrict__ y,
                                                 const float* __restrict__ g,
                                                 const float* __restrict__ be,
                                                 float* __restrict__ outf) {
    const int row = blockIdx.x;
    const int tid = threadIdx.x;
    const ushort4 xv = reinterpret_cast<const ushort4*>(x + (size_t)row * 1024)[tid];
    const ushort4 yv = reinterpret_cast<const ushort4*>(y + (size_t)row * 1024)[tid];
    float v[4] = {bf2f(xv.x) + bf2f(yv.x), bf2f(xv.y) + bf2f(yv.y),
                  bf2f(xv.z) + bf2f(yv.z), bf2f(xv.w) + bf2f(yv.w)};
    float s  = v[0] + v[1] + v[2] + v[3];
    float s2 = v[0]*v[0] + v[1]*v[1] + v[2]*v[2] + v[3]*v[3];
    for (int off = 32; off; off >>= 1) { s += __shfl_down(s, off); s2 += __shfl_down(s2, off); }
    __shared__ float red[8];
    const int w = tid >> 6, lane = tid & 63;
    if (lane == 0) { red[w] = s; red[4 + w] = s2; }
    __syncthreads();
    if (tid == 0) {
        const float ts  = red[0] + red[1] + red[2] + red[3];
        const float ts2 = red[4] + red[5] + red[6] + red[7];
        const float mu  = ts * (1.f / 1024.f);
        const float var = ts2 * (1.f / 1024.f) - mu * mu;
        red[0] = mu;
        red[1] = rsqrtf(var + 1e-5f);
    }
    __syncthreads();
    const float mu = red[0], rs = red[1];
    const float4 gv = reinterpret_cast<const float4*>(g)[tid];
    const float4 bv = reinterpret_cast<const float4*>(be)[tid];
    float4 of;
    of.x = (v[0] - mu) * rs * gv.x + bv.x;
    of.y = (v[1] - mu) * rs * gv.y + bv.y;
    of.z = (v[2] - mu) * rs * gv.z + bv.z;
    of.w = (v[3] - mu) * rs * gv.w + bv.w;
    reinterpret_cast<float4*>(outf + (size_t)row * 1024)[tid] = of;
}

// ---------- launch ----------
extern "C" void kernel_launch(void* const* d_in, const int* in_sizes, int n_in,
                              void* d_out, int out_size, void* d_ws, size_t ws_size,
                              hipStream_t stream) {
    const float* x  = (const float*)d_in[0];
    const float* Wq = (const float*)d_in[1];  const float* bq = (const float*)d_in[2];
    const float* Wk = (const float*)d_in[3];  const float* bk = (const float*)d_in[4];
    const float* Wv = (const float*)d_in[5];  const float* bv = (const float*)d_in[6];
    const float* Wo = (const float*)d_in[7];  const float* bo = (const float*)d_in[8];
    const float* W1 = (const float*)d_in[9];  const float* b1 = (const float*)d_in[10];
    const float* W2 = (const float*)d_in[11]; const float* b2 = (const float*)d_in[12];
    const float* g1 = (const float*)d_in[13]; const float* be1 = (const float*)d_in[14];
    const float* g2 = (const float*)d_in[15]; const float* be2 = (const float*)d_in[16];

    char* ws = (char*)d_ws;
    const size_t MBy = (size_t)1 << 20;
    ushort* xb    = (ushort*)(ws + 0 * MBy);     // 16 MB  [8192][1024] bf16
    ushort* wqkvT = (ushort*)(ws + 16 * MBy);    // 6 MB   [3072][1024]
    ushort* woT   = (ushort*)(ws + 22 * MBy);    // 2 MB
    ushort* w1T   = (ushort*)(ws + 24 * MBy);    // 8 MB   [4096][1024]
    ushort* w2T   = (ushort*)(ws + 32 * MBy);    // 8 MB   [1024][4096]
    ushort* QKVb  = (ushort*)(ws + 40 * MBy);    // 48 MB  [8192][3072]
    ushort* AOb   = (ushort*)(ws + 88 * MBy);    // 16 MB
    ushort* h1    = (ushort*)(ws + 40 * MBy);    // 64 MB (aliases QKVb+AOb, both dead by FFN1)
    ushort* y1b   = (ushort*)(ws + 104 * MBy);   // 16 MB
    ushort* y2b   = (ushort*)(ws + 104 * MBy);   // aliases y1b (dead after LN1)
    ushort* x2b   = (ushort*)(ws + 120 * MBy);   // 16 MB
    (void)ws_size; (void)n_in; (void)in_sizes; (void)out_size;

    const int M = 8192;

    cast_bf16_kernel<<<(M * 1024 / 4 + 255) / 256, 256, 0, stream>>>(x, xb, M * 1024 / 4);
    dim3 tb(32, 8);
    transpose_cast3_kernel<<<dim3(32, 32, 3), tb, 0, stream>>>(Wq, Wk, Wv, wqkvT);
    transpose_cast_kernel<<<dim3(32, 32),  tb, 0, stream>>>(Wo, woT, 1024, 1024);
    transpose_cast_kernel<<<dim3(128, 32), tb, 0, stream>>>(W1, w1T, 1024, 4096);
    transpose_cast_kernel<<<dim3(32, 128), tb, 0, stream>>>(W2, w2T, 4096, 1024);

    // QKV projection: M=8192 (32 row-tiles of 256), N=3072 (24 col-tiles) -> 768 blocks
    gemm_8p<0, 1, 1><<<dim3(24, 32), 512, 0, stream>>>(xb, wqkvT, bq, bk, bv, QKVb,
                                                       M, 3072, 1024);

    attn_kernel<<<1024, 256, 0, stream>>>(QKVb, AOb);

    // Wo: 8 x 32 = 256 blocks
    gemm_8p<0, 1, 0><<<dim3(8, 32), 512, 0, stream>>>(AOb, woT, bo, nullptr, nullptr, y1b,
                                                      M, 1024, 1024);

    ln_res_fb<<<M, 256, 0, stream>>>(x, y1b, g1, be1, x2b);

    // FFN1: 32 x 32 = 1024 blocks
    gemm_8p<1, 1, 0><<<dim3(32, 32), 512, 0, stream>>>(x2b, w1T, b1, nullptr, nullptr, h1,
                                                       M, 4096, 1024);
    // FFN2: K=4096 -> 64 K-tiles, 256 blocks
    gemm_8p<0, 1, 0><<<dim3(8, 32), 512, 0, stream>>>(h1, w2T, b2, nullptr, nullptr, y2b,
                                                      M, 1024, 4096);

    ln_res_bb<<<M, 256, 0, stream>>>(x2b, y2b, g2, be2, (float*)d_out);
}

// Round 10
// 408.085 us; speedup vs baseline: 1.0939x; 1.0939x over previous
//
#include <hip/hip_runtime.h>
#include <hip/hip_bf16.h>

// ---------- types ----------
typedef __attribute__((ext_vector_type(8)))  __bf16 bf16x8;
typedef __attribute__((ext_vector_type(4)))  float  f32x4;
typedef __attribute__((ext_vector_type(16))) float  f32x16;

static __device__ __forceinline__ unsigned short f2bf(float x) {
    unsigned int u = __float_as_uint(x);
    unsigned int r = (u + 0x7FFFu + ((u >> 16) & 1u)) >> 16;
    return (unsigned short)r;
}
static __device__ __forceinline__ float bf2f(unsigned short u) {
    return __uint_as_float(((unsigned int)u) << 16);
}

// 2^x via v_exp_f32. No s_nop: CDNA VALU has HW interlocks (trans-use hazard
// is RDNA3+ only); non-volatile so the scheduler can batch the 32 exps.
static __device__ __forceinline__ float fast_exp2(float x) {
    float r;
    asm("v_exp_f32 %0, %1" : "=v"(r) : "v"(x));
    return r;
}
// packed f32x2 -> bf16x2 (u32); lo <- a, hi <- b
static __device__ __forceinline__ unsigned int cvt_pk_bf16(float a, float b) {
    unsigned int r;
    asm("v_cvt_pk_bf16_f32 %0, %1, %2" : "=v"(r) : "v"(a), "v"(b));
    return r;
}

// async global->LDS, 16B per lane; lds base wave-uniform (lane*16 auto-offset)
static __device__ __forceinline__ void gload_lds16(const ushort* g, ushort* l) {
    __builtin_amdgcn_global_load_lds((const __attribute__((address_space(1))) void*)g,
                                     (__attribute__((address_space(3))) void*)l, 16, 0, 0);
}

// raw barrier + scheduling/memory fence (no vmcnt drain, unlike __syncthreads)
static __device__ __forceinline__ void barrier_fence() {
    __builtin_amdgcn_s_barrier();
    __builtin_amdgcn_sched_barrier(0);
    asm volatile("" ::: "memory");
}

// T1: XCD-aware chunked remap (requires nwg % 8 == 0; all grids here comply)
static __device__ __forceinline__ int xcd_swz(int id, int nwg) {
    return (id & 7) * (nwg >> 3) + (id >> 3);
}

// ---------- elementwise cast f32 -> bf16 ----------
__global__ __launch_bounds__(256) void cast_bf16_kernel(const float* __restrict__ in,
                                                        ushort* __restrict__ out, int n4) {
    int i = blockIdx.x * 256 + threadIdx.x;
    if (i < n4) {
        float4 v = reinterpret_cast<const float4*>(in)[i];
        ushort4 o;
        o.x = f2bf(v.x); o.y = f2bf(v.y); o.z = f2bf(v.z); o.w = f2bf(v.w);
        reinterpret_cast<ushort4*>(out)[i] = o;
    }
}

// ---------- transpose + cast: in[K][N] f32 -> out[N][K] bf16 ----------
__global__ __launch_bounds__(256) void transpose_cast_kernel(const float* __restrict__ in,
                                                             ushort* __restrict__ out,
                                                             int K, int N) {
    __shared__ float tile[32][33];
    const int tx = threadIdx.x;
    const int ty = threadIdx.y;
    const int n0 = blockIdx.x * 32;
    const int k0 = blockIdx.y * 32;
    for (int i = ty; i < 32; i += 8)
        tile[i][tx] = in[(size_t)(k0 + i) * N + n0 + tx];
    __syncthreads();
    for (int i = ty; i < 32; i += 8)
        out[(size_t)(n0 + i) * K + k0 + tx] = f2bf(tile[tx][i]);
}

// three 1024x1024 transposes (Wq,Wk,Wv) in one launch; z picks the source
__global__ __launch_bounds__(256) void transpose_cast3_kernel(const float* __restrict__ w0,
                                                              const float* __restrict__ w1,
                                                              const float* __restrict__ w2,
                                                              ushort* __restrict__ out) {
    __shared__ float tile[32][33];
    const int tx = threadIdx.x;
    const int ty = threadIdx.y;
    const int n0 = blockIdx.x * 32;
    const int k0 = blockIdx.y * 32;
    const int z  = blockIdx.z;
    const float* in = (z == 0) ? w0 : (z == 1 ? w1 : w2);
    ushort* o = out + (size_t)z * 1024 * 1024;
    for (int i = ty; i < 32; i += 8)
        tile[i][tx] = in[(size_t)(k0 + i) * 1024 + n0 + tx];
    __syncthreads();
    for (int i = ty; i < 32; i += 8)
        o[(size_t)(n0 + i) * 1024 + k0 + tx] = f2bf(tile[tx][i]);
}

// ============================================================================
// GEMM, 128x128 tile, BK=32, 256 threads (4 waves, 2x2 of 64x64).
// THREE LDS buffers (48KB -> 3 blocks/CU by LDS; 5 by VGPR), counted-vmcnt:
//   iter t: s_waitcnt vmcnt(4) ; s_barrier ; issue tile t+2 ; compute tile t.
// (round-8 structure, measured best). RES: 0 none, 1 add f32 residual,
// 2 add bf16 residual in the epilogue (fuses the pre-LN residual add).
// ============================================================================
template<int RELU, int OUTBF, int QKV, int RES>
__global__ __launch_bounds__(256) void gemm_p3(const ushort* __restrict__ A,
                                               const ushort* __restrict__ Bt,
                                               const float* __restrict__ b0,
                                               const float* __restrict__ b1_,
                                               const float* __restrict__ b2_,
                                               const void* __restrict__ xres,
                                               void* __restrict__ Cp,
                                               int M, int N, int K) {
    __shared__ ushort As[3][4096];
    __shared__ ushort Bs[3][4096];
    const int tid  = threadIdx.x;
    const int lane = tid & 63;
    const int w    = tid >> 6;
    const int wr   = w >> 1, wc = w & 1;
    const int nwg = gridDim.x * gridDim.y;
    int wid = xcd_swz(blockIdx.y * gridDim.x + blockIdx.x, nwg);
    const int bx = wid % gridDim.x;
    const int by = wid / gridDim.x;
    const int m0 = by * 128;
    const int n0 = bx * 128;
    const int lr = lane & 15;
    const int lk = (lane >> 4) * 8;

    const int r0 = w * 32 + (lane >> 2);
    const int c8 = (lane & 3) * 8;
    const ushort* gA0 = A  + (size_t)(m0 + r0)      * K + c8;
    const ushort* gA1 = A  + (size_t)(m0 + r0 + 16) * K + c8;
    const ushort* gB0 = Bt + (size_t)(n0 + r0)      * K + c8;
    const ushort* gB1 = Bt + (size_t)(n0 + r0 + 16) * K + c8;
    const int wb = w * 1024;

    f32x4 acc[4][4];
    const f32x4 z = {0.f, 0.f, 0.f, 0.f};
#pragma unroll
    for (int i = 0; i < 4; i++)
#pragma unroll
        for (int j = 0; j < 4; j++) acc[i][j] = z;

    const int nt = K >> 5;

    // prologue: issue tiles 0 and 1
#pragma unroll
    for (int t = 0; t < 2; ++t) {
        const int kn = t * 32;
        gload_lds16(gA0 + kn, &As[t][wb]);
        gload_lds16(gA1 + kn, &As[t][wb + 512]);
        gload_lds16(gB0 + kn, &Bs[t][wb]);
        gload_lds16(gB1 + kn, &Bs[t][wb + 512]);
    }

    int cur = 0;                       // t % 3
    for (int t = 0; t < nt; ++t) {
        if (t + 1 < nt) asm volatile("s_waitcnt vmcnt(4)" ::: "memory");
        else            asm volatile("s_waitcnt vmcnt(0)" ::: "memory");
        barrier_fence();

        if (t + 2 < nt) {
            const int bi = (cur + 2 >= 3) ? cur - 1 : cur + 2;   // (t+2)%3
            const int kn = (t + 2) * 32;
            gload_lds16(gA0 + kn, &As[bi][wb]);
            gload_lds16(gA1 + kn, &As[bi][wb + 512]);
            gload_lds16(gB0 + kn, &Bs[bi][wb]);
            gload_lds16(gB1 + kn, &Bs[bi][wb + 512]);
        }

        const ushort* Asb = As[cur];
        const ushort* Bsb = Bs[cur];
        bf16x8 af[4], bfr[4];
#pragma unroll
        for (int i = 0; i < 4; i++)
            af[i] = *reinterpret_cast<const bf16x8*>(&Asb[(wr * 64 + i * 16 + lr) * 32 + lk]);
#pragma unroll
        for (int j = 0; j < 4; j++)
            bfr[j] = *reinterpret_cast<const bf16x8*>(&Bsb[(wc * 64 + j * 16 + lr) * 32 + lk]);
#pragma unroll
        for (int i = 0; i < 4; i++)
#pragma unroll
            for (int j = 0; j < 4; j++)
                acc[i][j] = __builtin_amdgcn_mfma_f32_16x16x32_bf16(af[i], bfr[j], acc[i][j], 0, 0, 0);

        cur = (cur == 2) ? 0 : cur + 1;
    }

    // epilogue
    const float* bias;
    float qscale = 1.0f;
    if (QKV) {
        bias = (n0 < 1024) ? b0 : (n0 < 2048 ? b1_ : b2_);
        if (n0 < 1024) qscale = 0.18033688f;   // 0.125*log2(e) folded into Q
    } else {
        bias = b0;
    }
    const int nb = QKV ? (n0 & 1023) : n0;
    const int rbase = (lane >> 4) * 4;
#pragma unroll
    for (int i = 0; i < 4; i++) {
#pragma unroll
        for (int j = 0; j < 4; j++) {
            const int cloc = wc * 64 + j * 16 + lr;
            const float bv = bias[nb + cloc];
#pragma unroll
            for (int r = 0; r < 4; r++) {
                const int row = m0 + wr * 64 + i * 16 + rbase + r;
                float v = acc[i][j][r] + bv;
                if (RES == 1) v += ((const float*)xres)[(size_t)row * N + n0 + cloc];
                if (RES == 2) v += bf2f(((const ushort*)xres)[(size_t)row * N + n0 + cloc]);
                if (RELU) v = v > 0.f ? v : 0.f;
                if (QKV)  v *= qscale;
                if (OUTBF) ((ushort*)Cp)[(size_t)row * N + n0 + cloc] = f2bf(v);
                else       ((float*)Cp)[(size_t)row * N + n0 + cloc] = v;
            }
        }
    }
}

// ---------- flash attention, 32x32 swapped-QK^T, in-register P (T12) ----------
// V-transpose staging packs row-pairs (2t, 2t+1): adjacent t stay adjacent in
// the [d][t] layout after the XOR swizzle (it only flips col bits 3-5), so
// 16 ds_write_b16 become 8 ds_write_b32 (bank = tS2 ^ 4*((jj^ccS)&7): 2-way, free).
#define ASWZ(row, col) ((row) * 64 + ((col) ^ ((((row) ^ ((row) >> 3)) & 7) << 3)))

__global__ __launch_bounds__(256, 3) void attn_kernel(const ushort* __restrict__ QKV,
                                                      ushort* __restrict__ O) {
    __shared__ ushort Ks[2][4096];
    __shared__ ushort Vt[2][4096];
    const int tid  = threadIdx.x;
    const int lane = tid & 63;
    const int w    = tid >> 6;
    const int l31  = lane & 31;
    const int hi   = lane >> 5;

    int blk = xcd_swz(blockIdx.x, gridDim.x);
    const int qb = blk & 15;
    const int h  = (blk >> 4) & 15;
    const int b  = blk >> 8;
    const int s0 = qb * 128 + w * 32;
    const size_t rowb   = (size_t)b * 2048;
    const size_t base_q = rowb * 3072 + (size_t)h * 64;
    const size_t base_k = base_q + 1024;
    const size_t base_v = base_q + 2048;
    const size_t base_o = rowb * 1024 + (size_t)h * 64;

    bf16x8 qf[4];
#pragma unroll
    for (int ks = 0; ks < 4; ks++)
        qf[ks] = *reinterpret_cast<const bf16x8*>(
            &QKV[base_q + (size_t)(s0 + l31) * 3072 + ks * 16 + 8 * hi]);

    int off8[2][4];
#pragma unroll
    for (int sub = 0; sub < 2; sub++)
#pragma unroll
        for (int ks = 0; ks < 4; ks++)
            off8[sub][ks] = ASWZ(sub * 32 + l31, ks * 16 + 8 * hi);

    // staging geometry: K rows tS2 and tS2+32; V row-pair 2*tS2, 2*tS2+1
    const int tS2 = tid >> 3;          // 0..31
    const int ccS = tid & 7;
    int voff[8];
#pragma unroll
    for (int jj = 0; jj < 8; jj++)
        voff[jj] = ASWZ(ccS * 8 + jj, 2 * tS2);          // even; +1 = col 2*tS2+1
    const int tk1 = tS2 + 32;
    const int sz0 = (tS2 ^ (tS2 >> 3)) & 7;
    const int sz1 = (tk1 ^ (tk1 >> 3)) & 7;
    const ushort* pK0 = QKV + base_k + (size_t)tS2 * 3072 + (ccS ^ sz0) * 8;
    const ushort* pK1 = QKV + base_k + (size_t)tk1 * 3072 + (ccS ^ sz1) * 8;
    const ushort* pV0 = QKV + base_v + (size_t)(2 * tS2)     * 3072 + ccS * 8;
    const ushort* pV1 = QKV + base_v + (size_t)(2 * tS2 + 1) * 3072 + ccS * 8;
    const size_t step = (size_t)64 * 3072;

    gload_lds16(pK0, &Ks[0][w * 512]);
    gload_lds16(pK1, &Ks[0][2048 + w * 512]);
    {
        int4 v0 = *reinterpret_cast<const int4*>(pV0);
        int4 v1 = *reinterpret_cast<const int4*>(pV1);
        const ushort* vs0 = reinterpret_cast<const ushort*>(&v0);
        const ushort* vs1 = reinterpret_cast<const ushort*>(&v1);
#pragma unroll
        for (int jj = 0; jj < 8; jj++)
            *reinterpret_cast<unsigned*>(&Vt[0][voff[jj]]) =
                (unsigned)vs0[jj] | ((unsigned)vs1[jj] << 16);
    }
    pK0 += step; pK1 += step; pV0 += step; pV1 += step;
    __syncthreads();

    f32x16 oacc0, oacc1;
    for (int i = 0; i < 16; i++) { oacc0[i] = 0.f; oacc1[i] = 0.f; }
    float lacc = 0.f;
    int cur = 0;

    for (int it = 0; it < 32; ++it) {
        int4 nv0, nv1;
        if (it < 31) {
            gload_lds16(pK0, &Ks[cur ^ 1][w * 512]);
            gload_lds16(pK1, &Ks[cur ^ 1][2048 + w * 512]);
            nv0 = *reinterpret_cast<const int4*>(pV0);
            nv1 = *reinterpret_cast<const int4*>(pV1);
            pK0 += step; pK1 += step; pV0 += step; pV1 += step;
        }

        f32x16 sa0, sa1;
        for (int i = 0; i < 16; i++) { sa0[i] = 0.f; sa1[i] = 0.f; }
        __builtin_amdgcn_s_setprio(1);
#pragma unroll
        for (int ks = 0; ks < 4; ks++) {
            bf16x8 k0 = *reinterpret_cast<const bf16x8*>(&Ks[cur][off8[0][ks]]);
            sa0 = __builtin_amdgcn_mfma_f32_32x32x16_bf16(k0, qf[ks], sa0, 0, 0, 0);
        }
#pragma unroll
        for (int ks = 0; ks < 4; ks++) {
            bf16x8 k1 = *reinterpret_cast<const bf16x8*>(&Ks[cur][off8[1][ks]]);
            sa1 = __builtin_amdgcn_mfma_f32_32x32x16_bf16(k1, qf[ks], sa1, 0, 0, 0);
        }
        __builtin_amdgcn_s_setprio(0);

        unsigned pk0[8], pk1[8];
#pragma unroll
        for (int i = 0; i < 8; i++) {
            float plo = fast_exp2(sa0[2 * i]);
            float phi = fast_exp2(sa0[2 * i + 1]);
            lacc += plo + phi;
            pk0[i] = cvt_pk_bf16(plo, phi);
        }
#pragma unroll
        for (int i = 0; i < 8; i++) {
            float plo = fast_exp2(sa1[2 * i]);
            float phi = fast_exp2(sa1[2 * i + 1]);
            lacc += plo + phi;
            pk1[i] = cvt_pk_bf16(plo, phi);
        }

        __builtin_amdgcn_s_setprio(1);
#pragma unroll
        for (int ks = 0; ks < 4; ks++) {
            const int bi = 4 * (ks & 1);
            unsigned a, bb, c, d;
            if (ks < 2) { a = pk0[bi]; bb = pk0[bi + 1]; c = pk0[bi + 2]; d = pk0[bi + 3]; }
            else        { a = pk1[bi]; bb = pk1[bi + 1]; c = pk1[bi + 2]; d = pk1[bi + 3]; }
            asm("v_permlane32_swap_b32 %0, %1" : "+v"(a), "+v"(c));
            asm("v_permlane32_swap_b32 %0, %1" : "+v"(bb), "+v"(d));
            union { unsigned u[4]; bf16x8 v; } fr;
            fr.u[0] = a; fr.u[1] = bb; fr.u[2] = c; fr.u[3] = d;
            bf16x8 v0 = *reinterpret_cast<const bf16x8*>(&Vt[cur][off8[0][ks]]);
            oacc0 = __builtin_amdgcn_mfma_f32_32x32x16_bf16(fr.v, v0, oacc0, 0, 0, 0);
            bf16x8 v1 = *reinterpret_cast<const bf16x8*>(&Vt[cur][off8[1][ks]]);
            oacc1 = __builtin_amdgcn_mfma_f32_32x32x16_bf16(fr.v, v1, oacc1, 0, 0, 0);
        }
        __builtin_amdgcn_s_setprio(0);

        if (it < 31) {
            const ushort* vs0 = reinterpret_cast<const ushort*>(&nv0);
            const ushort* vs1 = reinterpret_cast<const ushort*>(&nv1);
#pragma unroll
            for (int jj = 0; jj < 8; jj++)
                *reinterpret_cast<unsigned*>(&Vt[cur ^ 1][voff[jj]]) =
                    (unsigned)vs0[jj] | ((unsigned)vs1[jj] << 16);
        }
        __syncthreads();
        cur ^= 1;
    }

    const float ltot = lacc + __shfl_xor(lacc, 32);
    const float inv  = 1.f / ltot;
#pragma unroll
    for (int r = 0; r < 16; r++) {
        const int qloc = (r & 3) + 8 * (r >> 2) + 4 * hi;
        const float invq = __shfl(inv, qloc);
        const size_t rowoff = base_o + (size_t)(s0 + qloc) * 1024 + l31;
        O[rowoff]      = f2bf(oacc0[r] * invq);
        O[rowoff + 32] = f2bf(oacc1[r] * invq);
    }
}

// ---------- single-input layernorm (residual already added in GEMM epilogue) ----------
template<int OUTBF>
__global__ __launch_bounds__(256) void ln_one(const ushort* __restrict__ zin,
                                              const float* __restrict__ g,
                                              const float* __restrict__ be,
                                              void* __restrict__ out) {
    const int row = blockIdx.x;
    const int tid = threadIdx.x;
    const ushort4 zv = reinterpret_cast<const ushort4*>(zin + (size_t)row * 1024)[tid];
    float v[4] = {bf2f(zv.x), bf2f(zv.y), bf2f(zv.z), bf2f(zv.w)};
    float s  = v[0] + v[1] + v[2] + v[3];
    float s2 = v[0]*v[0] + v[1]*v[1] + v[2]*v[2] + v[3]*v[3];
    for (int off = 32; off; off >>= 1) { s += __shfl_down(s, off); s2 += __shfl_down(s2, off); }
    __shared__ float red[8];
    const int w = tid >> 6, lane = tid & 63;
    if (lane == 0) { red[w] = s; red[4 + w] = s2; }
    __syncthreads();
    if (tid == 0) {
        const float ts  = red[0] + red[1] + red[2] + red[3];
        const float ts2 = red[4] + red[5] + red[6] + red[7];
        const float mu  = ts * (1.f / 1024.f);
        const float var = ts2 * (1.f / 1024.f) - mu * mu;
        red[0] = mu;
        red[1] = rsqrtf(var + 1e-5f);
    }
    __syncthreads();
    const float mu = red[0], rs = red[1];
    const float4 gv = reinterpret_cast<const float4*>(g)[tid];
    const float4 bv = reinterpret_cast<const float4*>(be)[tid];
    float o0 = (v[0] - mu) * rs * gv.x + bv.x;
    float o1 = (v[1] - mu) * rs * gv.y + bv.y;
    float o2 = (v[2] - mu) * rs * gv.z + bv.z;
    float o3 = (v[3] - mu) * rs * gv.w + bv.w;
    if (OUTBF) {
        ushort4 ob;
        ob.x = f2bf(o0); ob.y = f2bf(o1); ob.z = f2bf(o2); ob.w = f2bf(o3);
        reinterpret_cast<ushort4*>((ushort*)out + (size_t)row * 1024)[tid] = ob;
    } else {
        float4 of;
        of.x = o0; of.y = o1; of.z = o2; of.w = o3;
        reinterpret_cast<float4*>((float*)out + (size_t)row * 1024)[tid] = of;
    }
}

// ---------- launch ----------
extern "C" void kernel_launch(void* const* d_in, const int* in_sizes, int n_in,
                              void* d_out, int out_size, void* d_ws, size_t ws_size,
                              hipStream_t stream) {
    const float* x  = (const float*)d_in[0];
    const float* Wq = (const float*)d_in[1];  const float* bq = (const float*)d_in[2];
    const float* Wk = (const float*)d_in[3];  const float* bk = (const float*)d_in[4];
    const float* Wv = (const float*)d_in[5];  const float* bv = (const float*)d_in[6];
    const float* Wo = (const float*)d_in[7];  const float* bo = (const float*)d_in[8];
    const float* W1 = (const float*)d_in[9];  const float* b1 = (const float*)d_in[10];
    const float* W2 = (const float*)d_in[11]; const float* b2 = (const float*)d_in[12];
    const float* g1 = (const float*)d_in[13]; const float* be1 = (const float*)d_in[14];
    const float* g2 = (const float*)d_in[15]; const float* be2 = (const float*)d_in[16];

    char* ws = (char*)d_ws;
    const size_t MBy = (size_t)1 << 20;
    ushort* xb    = (ushort*)(ws + 0 * MBy);     // 16 MB  [8192][1024] bf16
    ushort* wqkvT = (ushort*)(ws + 16 * MBy);    // 6 MB   [3072][1024]
    ushort* woT   = (ushort*)(ws + 22 * MBy);    // 2 MB
    ushort* w1T   = (ushort*)(ws + 24 * MBy);    // 8 MB   [4096][1024]
    ushort* w2T   = (ushort*)(ws + 32 * MBy);    // 8 MB   [1024][4096]
    ushort* QKVb  = (ushort*)(ws + 40 * MBy);    // 48 MB  [8192][3072]
    ushort* AOb   = (ushort*)(ws + 88 * MBy);    // 16 MB
    ushort* h1    = (ushort*)(ws + 40 * MBy);    // 64 MB (aliases QKVb+AOb, both dead by FFN1)
    ushort* z1b   = (ushort*)(ws + 104 * MBy);   // 16 MB  x + attn_out (bf16)
    ushort* z2b   = (ushort*)(ws + 104 * MBy);   // aliases z1b (dead after LN1)
    ushort* x2b   = (ushort*)(ws + 120 * MBy);   // 16 MB
    (void)ws_size; (void)n_in; (void)in_sizes; (void)out_size;

    const int M = 8192;

    cast_bf16_kernel<<<(M * 1024 / 4 + 255) / 256, 256, 0, stream>>>(x, xb, M * 1024 / 4);
    dim3 tb(32, 8);
    transpose_cast3_kernel<<<dim3(32, 32, 3), tb, 0, stream>>>(Wq, Wk, Wv, wqkvT);
    transpose_cast_kernel<<<dim3(32, 32),  tb, 0, stream>>>(Wo, woT, 1024, 1024);
    transpose_cast_kernel<<<dim3(128, 32), tb, 0, stream>>>(W1, w1T, 1024, 4096);
    transpose_cast_kernel<<<dim3(32, 128), tb, 0, stream>>>(W2, w2T, 4096, 1024);

    // QKV projection
    gemm_p3<0, 1, 1, 0><<<dim3(24, 64), 256, 0, stream>>>(xb, wqkvT, bq, bk, bv, nullptr,
                                                          QKVb, M, 3072, 1024);

    attn_kernel<<<1024, 256, 0, stream>>>(QKVb, AOb);

    // Wo + fused residual (x, f32) -> z1 = x + attn_out (bf16)
    gemm_p3<0, 1, 0, 1><<<dim3(8, 64), 256, 0, stream>>>(AOb, woT, bo, nullptr, nullptr, x,
                                                         z1b, M, 1024, 1024);

    // LN1 (single input)
    ln_one<1><<<M, 256, 0, stream>>>(z1b, g1, be1, x2b);

    // FFN1
    gemm_p3<1, 1, 0, 0><<<dim3(32, 64), 256, 0, stream>>>(x2b, w1T, b1, nullptr, nullptr,
                                                          nullptr, h1, M, 4096, 1024);
    // FFN2 + fused residual (x2b, bf16) -> z2 = x2 + ffn_out (bf16)
    gemm_p3<0, 1, 0, 2><<<dim3(8, 64), 256, 0, stream>>>(h1, w2T, b2, nullptr, nullptr, x2b,
                                                         z2b, M, 1024, 4096);

    // LN2 -> d_out (f32)
    ln_one<0><<<M, 256, 0, stream>>>(z2b, g2, be2, (float*)d_out);
}

// Round 11
// 400.456 us; speedup vs baseline: 1.1147x; 1.0191x over previous
//
#include <hip/hip_runtime.h>
#include <hip/hip_bf16.h>

// ---------- types ----------
typedef __attribute__((ext_vector_type(8)))  __bf16 bf16x8;
typedef __attribute__((ext_vector_type(4)))  float  f32x4;
typedef __attribute__((ext_vector_type(16))) float  f32x16;

static __device__ __forceinline__ unsigned short f2bf(float x) {
    unsigned int u = __float_as_uint(x);
    unsigned int r = (u + 0x7FFFu + ((u >> 16) & 1u)) >> 16;
    return (unsigned short)r;
}
static __device__ __forceinline__ float bf2f(unsigned short u) {
    return __uint_as_float(((unsigned int)u) << 16);
}

// 2^x via v_exp_f32 (CDNA VALU has HW interlocks; no nop needed)
static __device__ __forceinline__ float fast_exp2(float x) {
    float r;
    asm("v_exp_f32 %0, %1" : "=v"(r) : "v"(x));
    return r;
}
// packed f32x2 -> bf16x2 (u32); lo <- a, hi <- b
static __device__ __forceinline__ unsigned int cvt_pk_bf16(float a, float b) {
    unsigned int r;
    asm("v_cvt_pk_bf16_f32 %0, %1, %2" : "=v"(r) : "v"(a), "v"(b));
    return r;
}

// async global->LDS, 16B per lane; lds base wave-uniform (lane*16 auto-offset)
static __device__ __forceinline__ void gload_lds16(const ushort* g, ushort* l) {
    __builtin_amdgcn_global_load_lds((const __attribute__((address_space(1))) void*)g,
                                     (__attribute__((address_space(3))) void*)l, 16, 0, 0);
}

// raw barrier + scheduling/memory fence (no vmcnt drain, unlike __syncthreads)
static __device__ __forceinline__ void barrier_fence() {
    __builtin_amdgcn_s_barrier();
    __builtin_amdgcn_sched_barrier(0);
    asm volatile("" ::: "memory");
}

// T1: XCD-aware chunked remap (requires nwg % 8 == 0; all grids here comply)
static __device__ __forceinline__ int xcd_swz(int id, int nwg) {
    return (id & 7) * (nwg >> 3) + (id >> 3);
}

// ---------- elementwise cast f32 -> bf16 ----------
__global__ __launch_bounds__(256) void cast_bf16_kernel(const float* __restrict__ in,
                                                        ushort* __restrict__ out, int n4) {
    int i = blockIdx.x * 256 + threadIdx.x;
    if (i < n4) {
        float4 v = reinterpret_cast<const float4*>(in)[i];
        ushort4 o;
        o.x = f2bf(v.x); o.y = f2bf(v.y); o.z = f2bf(v.z); o.w = f2bf(v.w);
        reinterpret_cast<ushort4*>(out)[i] = o;
    }
}

// ---------- transpose + cast: in[K][N] f32 -> out[N][K] bf16 ----------
__global__ __launch_bounds__(256) void transpose_cast_kernel(const float* __restrict__ in,
                                                             ushort* __restrict__ out,
                                                             int K, int N) {
    __shared__ float tile[32][33];
    const int tx = threadIdx.x;
    const int ty = threadIdx.y;
    const int n0 = blockIdx.x * 32;
    const int k0 = blockIdx.y * 32;
    for (int i = ty; i < 32; i += 8)
        tile[i][tx] = in[(size_t)(k0 + i) * N + n0 + tx];
    __syncthreads();
    for (int i = ty; i < 32; i += 8)
        out[(size_t)(n0 + i) * K + k0 + tx] = f2bf(tile[tx][i]);
}

// three 1024x1024 transposes (Wq,Wk,Wv) in one launch; z picks the source
__global__ __launch_bounds__(256) void transpose_cast3_kernel(const float* __restrict__ w0,
                                                              const float* __restrict__ w1,
                                                              const float* __restrict__ w2,
                                                              ushort* __restrict__ out) {
    __shared__ float tile[32][33];
    const int tx = threadIdx.x;
    const int ty = threadIdx.y;
    const int n0 = blockIdx.x * 32;
    const int k0 = blockIdx.y * 32;
    const int z  = blockIdx.z;
    const float* in = (z == 0) ? w0 : (z == 1 ? w1 : w2);
    ushort* o = out + (size_t)z * 1024 * 1024;
    for (int i = ty; i < 32; i += 8)
        tile[i][tx] = in[(size_t)(k0 + i) * 1024 + n0 + tx];
    __syncthreads();
    for (int i = ty; i < 32; i += 8)
        o[(size_t)(n0 + i) * 1024 + k0 + tx] = f2bf(tile[tx][i]);
}

// ============================================================================
// GEMM, 128x128 tile, BK=32, 256 threads (4 waves, 2x2 of 64x64).
// 3 LDS buffers, counted-vmcnt pipeline (round-8 structure, measured best):
//   iter t: s_waitcnt vmcnt(4) ; s_barrier ; issue tile t+2 ; compute tile t.
// T2 bank-conflict swizzle: [128][32] linear gives bank = (16*row+4*chunk)%32
// -> a b128 fragment column (16 lanes, rows +lr) hits 2 bank-quads = 8-way.
// Swizzle s(row) = (row>>1)&3 on the 16B-chunk index, BOTH sides (rule 21):
//   write: global source chunk ^= s(row) (gload dest stays linear);
//   read:  chunk = lg ^ s(row)  ->  all 8 bank-quads, 2 lanes each = free.
// For the staging map (r0 = w*32 + lane>>2), s(r0) == (lane>>3)&3, and
// s(r0+16) == s(r0), so one per-thread XOR serves both A row-loads.
// For fragment reads (row = base + lr, base%16==0), s(row) == (lr>>1)&3.
// ============================================================================
template<int RELU, int OUTBF, int QKV, int RES>
__global__ __launch_bounds__(256) void gemm_p3(const ushort* __restrict__ A,
                                               const ushort* __restrict__ Bt,
                                               const float* __restrict__ b0,
                                               const float* __restrict__ b1_,
                                               const float* __restrict__ b2_,
                                               const void* __restrict__ xres,
                                               void* __restrict__ Cp,
                                               int M, int N, int K) {
    __shared__ ushort As[3][4096];
    __shared__ ushort Bs[3][4096];
    const int tid  = threadIdx.x;
    const int lane = tid & 63;
    const int w    = tid >> 6;
    const int wr   = w >> 1, wc = w & 1;
    const int nwg = gridDim.x * gridDim.y;
    int wid = xcd_swz(blockIdx.y * gridDim.x + blockIdx.x, nwg);
    const int bx = wid % gridDim.x;
    const int by = wid / gridDim.x;
    const int m0 = by * 128;
    const int n0 = bx * 128;
    const int lr = lane & 15;
    const int lg = lane >> 4;                      // k-octet 0..3
    const int xc = (lg ^ ((lr >> 1) & 3)) * 8;     // swizzled read chunk (elements)

    const int r0 = w * 32 + (lane >> 2);
    const int c8 = ((lane & 3) ^ ((lane >> 3) & 3)) * 8;   // pre-swizzled source chunk
    const ushort* gA0 = A  + (size_t)(m0 + r0)      * K + c8;
    const ushort* gA1 = A  + (size_t)(m0 + r0 + 16) * K + c8;
    const ushort* gB0 = Bt + (size_t)(n0 + r0)      * K + c8;
    const ushort* gB1 = Bt + (size_t)(n0 + r0 + 16) * K + c8;
    const int wb = w * 1024;

    f32x4 acc[4][4];
    const f32x4 z = {0.f, 0.f, 0.f, 0.f};
#pragma unroll
    for (int i = 0; i < 4; i++)
#pragma unroll
        for (int j = 0; j < 4; j++) acc[i][j] = z;

    const int nt = K >> 5;

    // prologue: issue tiles 0 and 1
#pragma unroll
    for (int t = 0; t < 2; ++t) {
        const int kn = t * 32;
        gload_lds16(gA0 + kn, &As[t][wb]);
        gload_lds16(gA1 + kn, &As[t][wb + 512]);
        gload_lds16(gB0 + kn, &Bs[t][wb]);
        gload_lds16(gB1 + kn, &Bs[t][wb + 512]);
    }

    int cur = 0;                       // t % 3
    for (int t = 0; t < nt; ++t) {
        if (t + 1 < nt) asm volatile("s_waitcnt vmcnt(4)" ::: "memory");
        else            asm volatile("s_waitcnt vmcnt(0)" ::: "memory");
        barrier_fence();

        if (t + 2 < nt) {
            const int bi = (cur + 2 >= 3) ? cur - 1 : cur + 2;   // (t+2)%3
            const int kn = (t + 2) * 32;
            gload_lds16(gA0 + kn, &As[bi][wb]);
            gload_lds16(gA1 + kn, &As[bi][wb + 512]);
            gload_lds16(gB0 + kn, &Bs[bi][wb]);
            gload_lds16(gB1 + kn, &Bs[bi][wb + 512]);
        }

        const ushort* Asb = As[cur];
        const ushort* Bsb = Bs[cur];
        bf16x8 af[4], bfr[4];
#pragma unroll
        for (int i = 0; i < 4; i++)
            af[i] = *reinterpret_cast<const bf16x8*>(&Asb[(wr * 64 + i * 16 + lr) * 32 + xc]);
#pragma unroll
        for (int j = 0; j < 4; j++)
            bfr[j] = *reinterpret_cast<const bf16x8*>(&Bsb[(wc * 64 + j * 16 + lr) * 32 + xc]);
#pragma unroll
        for (int i = 0; i < 4; i++)
#pragma unroll
            for (int j = 0; j < 4; j++)
                acc[i][j] = __builtin_amdgcn_mfma_f32_16x16x32_bf16(af[i], bfr[j], acc[i][j], 0, 0, 0);

        cur = (cur == 2) ? 0 : cur + 1;
    }

    // epilogue
    const float* bias;
    float qscale = 1.0f;
    if (QKV) {
        bias = (n0 < 1024) ? b0 : (n0 < 2048 ? b1_ : b2_);
        if (n0 < 1024) qscale = 0.18033688f;   // 0.125*log2(e) folded into Q
    } else {
        bias = b0;
    }
    const int nb = QKV ? (n0 & 1023) : n0;
    const int rbase = (lane >> 4) * 4;
#pragma unroll
    for (int i = 0; i < 4; i++) {
#pragma unroll
        for (int j = 0; j < 4; j++) {
            const int cloc = wc * 64 + j * 16 + lr;
            const float bv = bias[nb + cloc];
#pragma unroll
            for (int r = 0; r < 4; r++) {
                const int row = m0 + wr * 64 + i * 16 + rbase + r;
                float v = acc[i][j][r] + bv;
                if (RES == 1) v += ((const float*)xres)[(size_t)row * N + n0 + cloc];
                if (RES == 2) v += bf2f(((const ushort*)xres)[(size_t)row * N + n0 + cloc]);
                if (RELU) v = v > 0.f ? v : 0.f;
                if (QKV)  v *= qscale;
                if (OUTBF) ((ushort*)Cp)[(size_t)row * N + n0 + cloc] = f2bf(v);
                else       ((float*)Cp)[(size_t)row * N + n0 + cloc] = v;
            }
        }
    }
}

// ---------- flash attention, 32x32 swapped-QK^T, in-register P (T12) ----------
#define ASWZ(row, col) ((row) * 64 + ((col) ^ ((((row) ^ ((row) >> 3)) & 7) << 3)))

__global__ __launch_bounds__(256, 3) void attn_kernel(const ushort* __restrict__ QKV,
                                                      ushort* __restrict__ O) {
    __shared__ ushort Ks[2][4096];
    __shared__ ushort Vt[2][4096];
    const int tid  = threadIdx.x;
    const int lane = tid & 63;
    const int w    = tid >> 6;
    const int l31  = lane & 31;
    const int hi   = lane >> 5;

    int blk = xcd_swz(blockIdx.x, gridDim.x);
    const int qb = blk & 15;
    const int h  = (blk >> 4) & 15;
    const int b  = blk >> 8;
    const int s0 = qb * 128 + w * 32;
    const size_t rowb   = (size_t)b * 2048;
    const size_t base_q = rowb * 3072 + (size_t)h * 64;
    const size_t base_k = base_q + 1024;
    const size_t base_v = base_q + 2048;
    const size_t base_o = rowb * 1024 + (size_t)h * 64;

    bf16x8 qf[4];
#pragma unroll
    for (int ks = 0; ks < 4; ks++)
        qf[ks] = *reinterpret_cast<const bf16x8*>(
            &QKV[base_q + (size_t)(s0 + l31) * 3072 + ks * 16 + 8 * hi]);

    int off8[2][4];
#pragma unroll
    for (int sub = 0; sub < 2; sub++)
#pragma unroll
        for (int ks = 0; ks < 4; ks++)
            off8[sub][ks] = ASWZ(sub * 32 + l31, ks * 16 + 8 * hi);

    // staging geometry: K rows tS2 and tS2+32; V row-pair 2*tS2, 2*tS2+1
    const int tS2 = tid >> 3;          // 0..31
    const int ccS = tid & 7;
    int voff[8];
#pragma unroll
    for (int jj = 0; jj < 8; jj++)
        voff[jj] = ASWZ(ccS * 8 + jj, 2 * tS2);          // even; +1 = col 2*tS2+1
    const int tk1 = tS2 + 32;
    const int sz0 = (tS2 ^ (tS2 >> 3)) & 7;
    const int sz1 = (tk1 ^ (tk1 >> 3)) & 7;
    const ushort* pK0 = QKV + base_k + (size_t)tS2 * 3072 + (ccS ^ sz0) * 8;
    const ushort* pK1 = QKV + base_k + (size_t)tk1 * 3072 + (ccS ^ sz1) * 8;
    const ushort* pV0 = QKV + base_v + (size_t)(2 * tS2)     * 3072 + ccS * 8;
    const ushort* pV1 = QKV + base_v + (size_t)(2 * tS2 + 1) * 3072 + ccS * 8;
    const size_t step = (size_t)64 * 3072;

    gload_lds16(pK0, &Ks[0][w * 512]);
    gload_lds16(pK1, &Ks[0][2048 + w * 512]);
    {
        int4 v0 = *reinterpret_cast<const int4*>(pV0);
        int4 v1 = *reinterpret_cast<const int4*>(pV1);
        const ushort* vs0 = reinterpret_cast<const ushort*>(&v0);
        const ushort* vs1 = reinterpret_cast<const ushort*>(&v1);
#pragma unroll
        for (int jj = 0; jj < 8; jj++)
            *reinterpret_cast<unsigned*>(&Vt[0][voff[jj]]) =
                (unsigned)vs0[jj] | ((unsigned)vs1[jj] << 16);
    }
    pK0 += step; pK1 += step; pV0 += step; pV1 += step;
    __syncthreads();

    f32x16 oacc0, oacc1;
    for (int i = 0; i < 16; i++) { oacc0[i] = 0.f; oacc1[i] = 0.f; }
    float lacc = 0.f;
    int cur = 0;

    for (int it = 0; it < 32; ++it) {
        int4 nv0, nv1;
        if (it < 31) {
            gload_lds16(pK0, &Ks[cur ^ 1][w * 512]);
            gload_lds16(pK1, &Ks[cur ^ 1][2048 + w * 512]);
            nv0 = *reinterpret_cast<const int4*>(pV0);
            nv1 = *reinterpret_cast<const int4*>(pV1);
            pK0 += step; pK1 += step; pV0 += step; pV1 += step;
        }

        f32x16 sa0, sa1;
        for (int i = 0; i < 16; i++) { sa0[i] = 0.f; sa1[i] = 0.f; }
        __builtin_amdgcn_s_setprio(1);
#pragma unroll
        for (int ks = 0; ks < 4; ks++) {
            bf16x8 k0 = *reinterpret_cast<const bf16x8*>(&Ks[cur][off8[0][ks]]);
            sa0 = __builtin_amdgcn_mfma_f32_32x32x16_bf16(k0, qf[ks], sa0, 0, 0, 0);
        }
#pragma unroll
        for (int ks = 0; ks < 4; ks++) {
            bf16x8 k1 = *reinterpret_cast<const bf16x8*>(&Ks[cur][off8[1][ks]]);
            sa1 = __builtin_amdgcn_mfma_f32_32x32x16_bf16(k1, qf[ks], sa1, 0, 0, 0);
        }
        __builtin_amdgcn_s_setprio(0);

        unsigned pk0[8], pk1[8];
#pragma unroll
        for (int i = 0; i < 8; i++) {
            float plo = fast_exp2(sa0[2 * i]);
            float phi = fast_exp2(sa0[2 * i + 1]);
            lacc += plo + phi;
            pk0[i] = cvt_pk_bf16(plo, phi);
        }
#pragma unroll
        for (int i = 0; i < 8; i++) {
            float plo = fast_exp2(sa1[2 * i]);
            float phi = fast_exp2(sa1[2 * i + 1]);
            lacc += plo + phi;
            pk1[i] = cvt_pk_bf16(plo, phi);
        }

        __builtin_amdgcn_s_setprio(1);
#pragma unroll
        for (int ks = 0; ks < 4; ks++) {
            const int bi = 4 * (ks & 1);
            unsigned a, bb, c, d;
            if (ks < 2) { a = pk0[bi]; bb = pk0[bi + 1]; c = pk0[bi + 2]; d = pk0[bi + 3]; }
            else        { a = pk1[bi]; bb = pk1[bi + 1]; c = pk1[bi + 2]; d = pk1[bi + 3]; }
            asm("v_permlane32_swap_b32 %0, %1" : "+v"(a), "+v"(c));
            asm("v_permlane32_swap_b32 %0, %1" : "+v"(bb), "+v"(d));
            union { unsigned u[4]; bf16x8 v; } fr;
            fr.u[0] = a; fr.u[1] = bb; fr.u[2] = c; fr.u[3] = d;
            bf16x8 v0 = *reinterpret_cast<const bf16x8*>(&Vt[cur][off8[0][ks]]);
            oacc0 = __builtin_amdgcn_mfma_f32_32x32x16_bf16(fr.v, v0, oacc0, 0, 0, 0);
            bf16x8 v1 = *reinterpret_cast<const bf16x8*>(&Vt[cur][off8[1][ks]]);
            oacc1 = __builtin_amdgcn_mfma_f32_32x32x16_bf16(fr.v, v1, oacc1, 0, 0, 0);
        }
        __builtin_amdgcn_s_setprio(0);

        if (it < 31) {
            const ushort* vs0 = reinterpret_cast<const ushort*>(&nv0);
            const ushort* vs1 = reinterpret_cast<const ushort*>(&nv1);
#pragma unroll
            for (int jj = 0; jj < 8; jj++)
                *reinterpret_cast<unsigned*>(&Vt[cur ^ 1][voff[jj]]) =
                    (unsigned)vs0[jj] | ((unsigned)vs1[jj] << 16);
        }
        __syncthreads();
        cur ^= 1;
    }

    const float ltot = lacc + __shfl_xor(lacc, 32);
    const float inv  = 1.f / ltot;
#pragma unroll
    for (int r = 0; r < 16; r++) {
        const int qloc = (r & 3) + 8 * (r >> 2) + 4 * hi;
        const float invq = __shfl(inv, qloc);
        const size_t rowoff = base_o + (size_t)(s0 + qloc) * 1024 + l31;
        O[rowoff]      = f2bf(oacc0[r] * invq);
        O[rowoff + 32] = f2bf(oacc1[r] * invq);
    }
}

// ---------- single-input layernorm (residual already added in GEMM epilogue) ----------
template<int OUTBF>
__global__ __launch_bounds__(256) void ln_one(const ushort* __restrict__ zin,
                                              const float* __restrict__ g,
                                              const float* __restrict__ be,
                                              void* __restrict__ out) {
    const int row = blockIdx.x;
    const int tid = threadIdx.x;
    const ushort4 zv = reinterpret_cast<const ushort4*>(zin + (size_t)row * 1024)[tid];
    float v[4] = {bf2f(zv.x), bf2f(zv.y), bf2f(zv.z), bf2f(zv.w)};
    float s  = v[0] + v[1] + v[2] + v[3];
    float s2 = v[0]*v[0] + v[1]*v[1] + v[2]*v[2] + v[3]*v[3];
    for (int off = 32; off; off >>= 1) { s += __shfl_down(s, off); s2 += __shfl_down(s2, off); }
    __shared__ float red[8];
    const int w = tid >> 6, lane = tid & 63;
    if (lane == 0) { red[w] = s; red[4 + w] = s2; }
    __syncthreads();
    if (tid == 0) {
        const float ts  = red[0] + red[1] + red[2] + red[3];
        const float ts2 = red[4] + red[5] + red[6] + red[7];
        const float mu  = ts * (1.f / 1024.f);
        const float var = ts2 * (1.f / 1024.f) - mu * mu;
        red[0] = mu;
        red[1] = rsqrtf(var + 1e-5f);
    }
    __syncthreads();
    const float mu = red[0], rs = red[1];
    const float4 gv = reinterpret_cast<const float4*>(g)[tid];
    const float4 bv = reinterpret_cast<const float4*>(be)[tid];
    float o0 = (v[0] - mu) * rs * gv.x + bv.x;
    float o1 = (v[1] - mu) * rs * gv.y + bv.y;
    float o2 = (v[2] - mu) * rs * gv.z + bv.z;
    float o3 = (v[3] - mu) * rs * gv.w + bv.w;
    if (OUTBF) {
        ushort4 ob;
        ob.x = f2bf(o0); ob.y = f2bf(o1); ob.z = f2bf(o2); ob.w = f2bf(o3);
        reinterpret_cast<ushort4*>((ushort*)out + (size_t)row * 1024)[tid] = ob;
    } else {
        float4 of;
        of.x = o0; of.y = o1; of.z = o2; of.w = o3;
        reinterpret_cast<float4*>((float*)out + (size_t)row * 1024)[tid] = of;
    }
}

// ---------- launch ----------
extern "C" void kernel_launch(void* const* d_in, const int* in_sizes, int n_in,
                              void* d_out, int out_size, void* d_ws, size_t ws_size,
                              hipStream_t stream) {
    const float* x  = (const float*)d_in[0];
    const float* Wq = (const float*)d_in[1];  const float* bq = (const float*)d_in[2];
    const float* Wk = (const float*)d_in[3];  const float* bk = (const float*)d_in[4];
    const float* Wv = (const float*)d_in[5];  const float* bv = (const float*)d_in[6];
    const float* Wo = (const float*)d_in[7];  const float* bo = (const float*)d_in[8];
    const float* W1 = (const float*)d_in[9];  const float* b1 = (const float*)d_in[10];
    const float* W2 = (const float*)d_in[11]; const float* b2 = (const float*)d_in[12];
    const float* g1 = (const float*)d_in[13]; const float* be1 = (const float*)d_in[14];
    const float* g2 = (const float*)d_in[15]; const float* be2 = (const float*)d_in[16];

    char* ws = (char*)d_ws;
    const size_t MBy = (size_t)1 << 20;
    ushort* xb    = (ushort*)(ws + 0 * MBy);     // 16 MB  [8192][1024] bf16
    ushort* wqkvT = (ushort*)(ws + 16 * MBy);    // 6 MB   [3072][1024]
    ushort* woT   = (ushort*)(ws + 22 * MBy);    // 2 MB
    ushort* w1T   = (ushort*)(ws + 24 * MBy);    // 8 MB   [4096][1024]
    ushort* w2T   = (ushort*)(ws + 32 * MBy);    // 8 MB   [1024][4096]
    ushort* QKVb  = (ushort*)(ws + 40 * MBy);    // 48 MB  [8192][3072]
    ushort* AOb   = (ushort*)(ws + 88 * MBy);    // 16 MB
    ushort* h1    = (ushort*)(ws + 40 * MBy);    // 64 MB (aliases QKVb+AOb, both dead by FFN1)
    ushort* z1b   = (ushort*)(ws + 104 * MBy);   // 16 MB  x + attn_out (bf16)
    ushort* z2b   = (ushort*)(ws + 104 * MBy);   // aliases z1b (dead after LN1)
    ushort* x2b   = (ushort*)(ws + 120 * MBy);   // 16 MB
    (void)ws_size; (void)n_in; (void)in_sizes; (void)out_size;

    const int M = 8192;

    cast_bf16_kernel<<<(M * 1024 / 4 + 255) / 256, 256, 0, stream>>>(x, xb, M * 1024 / 4);
    dim3 tb(32, 8);
    transpose_cast3_kernel<<<dim3(32, 32, 3), tb, 0, stream>>>(Wq, Wk, Wv, wqkvT);
    transpose_cast_kernel<<<dim3(32, 32),  tb, 0, stream>>>(Wo, woT, 1024, 1024);
    transpose_cast_kernel<<<dim3(128, 32), tb, 0, stream>>>(W1, w1T, 1024, 4096);
    transpose_cast_kernel<<<dim3(32, 128), tb, 0, stream>>>(W2, w2T, 4096, 1024);

    // QKV projection
    gemm_p3<0, 1, 1, 0><<<dim3(24, 64), 256, 0, stream>>>(xb, wqkvT, bq, bk, bv, nullptr,
                                                          QKVb, M, 3072, 1024);

    attn_kernel<<<1024, 256, 0, stream>>>(QKVb, AOb);

    // Wo + fused residual (x, f32) -> z1 = x + attn_out (bf16)
    gemm_p3<0, 1, 0, 1><<<dim3(8, 64), 256, 0, stream>>>(AOb, woT, bo, nullptr, nullptr, x,
                                                         z1b, M, 1024, 1024);

    // LN1 (single input)
    ln_one<1><<<M, 256, 0, stream>>>(z1b, g1, be1, x2b);

    // FFN1
    gemm_p3<1, 1, 0, 0><<<dim3(32, 64), 256, 0, stream>>>(x2b, w1T, b1, nullptr, nullptr,
                                                          nullptr, h1, M, 4096, 1024);
    // FFN2 + fused residual (x2b, bf16) -> z2 = x2 + ffn_out (bf16)
    gemm_p3<0, 1, 0, 2><<<dim3(8, 64), 256, 0, stream>>>(h1, w2T, b2, nullptr, nullptr, x2b,
                                                         z2b, M, 1024, 4096);

    // LN2 -> d_out (f32)
    ln_one<0><<<M, 256, 0, stream>>>(z2b, g2, be2, (float*)d_out);
}